// Round 5
// baseline (2670.712 us; speedup 1.0000x reference)
//
#include <hip/hip_runtime.h>
#include <hip/hip_bf16.h>

#define EMB_D 100
#define HID 64
#define G4 256
#define BATCH 128
#define SEQ 1024
#define TOK 16
#define ROWS 4

__device__ __forceinline__ float sigf(float x) { return 1.0f / (1.0f + __expf(-x)); }
__device__ __forceinline__ float tanh_fast(float x) {
  float t = __expf(-2.0f * fabsf(x));
  float r = (1.0f - t) / (1.0f + t);
  return copysignf(r, x);
}

// --- prep: combined biases + transposed Wih0 (for coalesced access) ---
__global__ void prep_kernel(const float* __restrict__ Wih0,
                            const float* __restrict__ bih0, const float* __restrict__ bhh0,
                            const float* __restrict__ bih1, const float* __restrict__ bhh1,
                            float* __restrict__ Wih0T, float* __restrict__ b0c,
                            float* __restrict__ b1c) {
  int g = threadIdx.x;
  b0c[g] = bih0[g] + bhh0[g];
  b1c[g] = bih1[g] + bhh1[g];
  for (int d = 0; d < EMB_D; ++d) Wih0T[d * G4 + g] = Wih0[g * EMB_D + d];
}

// --- xw0[token][gate] = emb[x[token]] . Wih0[gate] + b0 --- (unchanged)
__global__ __attribute__((amdgpu_waves_per_eu(1, 4))) __launch_bounds__(256)
void xw0_kernel(
    const int* __restrict__ x, const float* __restrict__ emb,
    const float* __restrict__ Wih0T, const float* __restrict__ b0c,
    float* __restrict__ xw0) {
  __shared__ int sidx[TOK];
  __shared__ float erow[TOK][EMB_D];
  int g = threadIdx.x;
  long t0 = (long)blockIdx.x * TOK;

  if (g < TOK) sidx[g] = x[t0 + g];
  __syncthreads();
  for (int i = g; i < TOK * EMB_D; i += 256) {
    int tok = i / EMB_D;
    int d = i - tok * EMB_D;
    erow[tok][d] = emb[(long)sidx[tok] * EMB_D + d];
  }

  float w[EMB_D];
  #pragma unroll
  for (int d = 0; d < EMB_D; ++d) w[d] = Wih0T[d * G4 + g];
  #pragma unroll
  for (int d = 0; d < EMB_D; d += 4) {
    asm volatile("" : "+v"(w[d]), "+v"(w[d + 1]), "+v"(w[d + 2]), "+v"(w[d + 3]));
  }
  float bb = b0c[g];
  __syncthreads();

  for (int tok = 0; tok < TOK; ++tok) {
    const float* ev = erow[tok];
    float a0 = bb, a1 = 0.f, a2 = 0.f, a3 = 0.f;
    #pragma unroll
    for (int d = 0; d < EMB_D; d += 4) {
      a0 = fmaf(w[d],     ev[d],     a0);
      a1 = fmaf(w[d + 1], ev[d + 1], a1);
      a2 = fmaf(w[d + 2], ev[d + 2], a2);
      a3 = fmaf(w[d + 3], ev[d + 3], a3);
    }
    xw0[(t0 + tok) * G4 + g] = (a0 + a1) + (a2 + a3);
  }
}

// --- fused 2-layer recurrence + classifier head, ROWS=4 rows per block ---
// 32 blocks, 512 threads. GEMV role: (g = tid&255, hb = tid>>8) — same
// weights reused across 4 rows (4x work per thread amortizes the per-step
// barrier/activation/latency overhead). Act role: (row ar = tid>>7,
// layer alay = (tid>>6)&1, elem aj = tid&63) — ALL threads activate.
__global__ __attribute__((amdgpu_waves_per_eu(1, 2))) __launch_bounds__(512)
void lstm_fused_kernel(
    const float* __restrict__ xw0,
    const float* __restrict__ Whh0, const float* __restrict__ Wih1,
    const float* __restrict__ Whh1, const float* __restrict__ b1c,
    const float* __restrict__ W1, const float* __restrict__ clsb1,
    const float* __restrict__ W2, const float* __restrict__ clsb2,
    float* __restrict__ out) {
  int tid = threadIdx.x;
  int g = tid & 255;
  int hb = tid >> 8;
  int brow0 = blockIdx.x * ROWS;
  int ar = tid >> 7;
  int alay = (tid >> 6) & 1;
  int aj = tid & 63;

  // 96 weight floats per thread (pinned in VGPRs)
  float w0[32], w1[32], w2[32];
  {
    const float4* p0 = (const float4*)(Whh0 + g * HID + hb * 32);
    const float4* p1 = (const float4*)(Wih1 + g * HID + hb * 32);
    const float4* p2 = (const float4*)(Whh1 + g * HID + hb * 32);
    #pragma unroll
    for (int c = 0; c < 8; ++c) {
      float4 v0 = p0[c], v1 = p1[c], v2 = p2[c];
      w0[4*c] = v0.x; w0[4*c+1] = v0.y; w0[4*c+2] = v0.z; w0[4*c+3] = v0.w;
      w1[4*c] = v1.x; w1[4*c+1] = v1.y; w1[4*c+2] = v1.z; w1[4*c+3] = v1.w;
      w2[4*c] = v2.x; w2[4*c+1] = v2.y; w2[4*c+2] = v2.z; w2[4*c+3] = v2.w;
    }
  }
  #pragma unroll
  for (int k = 0; k < 32; k += 4) {
    asm volatile("" : "+v"(w0[k]), "+v"(w0[k+1]), "+v"(w0[k+2]), "+v"(w0[k+3]));
    asm volatile("" : "+v"(w1[k]), "+v"(w1[k+1]), "+v"(w1[k+2]), "+v"(w1[k+3]));
    asm volatile("" : "+v"(w2[k]), "+v"(w2[k+1]), "+v"(w2[k+2]), "+v"(w2[k+3]));
  }

  __shared__ float h0s[ROWS][HID];
  __shared__ float h1s[ROWS][HID];
  __shared__ float gp0[ROWS][512];
  __shared__ float gp1[ROWS][512];
  __shared__ float zs[ROWS][HID];

  if (tid < ROWS * HID) {
    ((float*)h0s)[tid] = 0.f;
    ((float*)h1s)[tid] = 0.f;
  }
  float c_reg = 0.f;                       // c-state for (ar, alay, aj)
  float bias1 = (hb == 0) ? b1c[g] : 0.f;

  // distance-3 xw prefetch, 4 rows, held by hb==0 threads
  float xwA[ROWS], xwB[ROWS], xwC[ROWS];
  const float* xbase = xw0 + (long)brow0 * SEQ * G4 + g;
  #pragma unroll
  for (int r = 0; r < ROWS; ++r) { xwA[r] = 0.f; xwB[r] = 0.f; xwC[r] = 0.f; }
  if (hb == 0) {
    #pragma unroll
    for (int r = 0; r < ROWS; ++r) {
      const float* xr = xbase + (long)r * SEQ * G4;
      xwA[r] = xr[0];
      xwB[r] = xr[G4];
      xwC[r] = xr[2 * G4];
    }
  }
  __syncthreads();

  for (int t = 0; t < SEQ; ++t) {
    int tn = (t + 3 < SEQ) ? (t + 3) : (SEQ - 1);
    float xwD[ROWS];
    #pragma unroll
    for (int r = 0; r < ROWS; ++r) xwD[r] = 0.f;
    if (hb == 0) {
      #pragma unroll
      for (int r = 0; r < ROWS; ++r)
        xwD[r] = xbase[(long)r * SEQ * G4 + (long)tn * G4];
    }

    float a[ROWS], d[ROWS];
    #pragma unroll
    for (int r = 0; r < ROWS; ++r) {
      a[r] = (hb == 0) ? xwA[r] : 0.f;
      d[r] = bias1;
    }
    #pragma unroll
    for (int c = 0; c < 8; ++c) {
      #pragma unroll
      for (int r = 0; r < ROWS; ++r) {
        float4 hv0 = *(const float4*)&h0s[r][hb * 32 + c * 4];
        float4 hv1 = *(const float4*)&h1s[r][hb * 32 + c * 4];
        a[r] = fmaf(hv0.x, w0[4*c],   a[r]);
        a[r] = fmaf(hv0.y, w0[4*c+1], a[r]);
        a[r] = fmaf(hv0.z, w0[4*c+2], a[r]);
        a[r] = fmaf(hv0.w, w0[4*c+3], a[r]);
        d[r] = fmaf(hv0.x, w1[4*c],   d[r]);
        d[r] = fmaf(hv0.y, w1[4*c+1], d[r]);
        d[r] = fmaf(hv0.z, w1[4*c+2], d[r]);
        d[r] = fmaf(hv0.w, w1[4*c+3], d[r]);
        d[r] = fmaf(hv1.x, w2[4*c],   d[r]);
        d[r] = fmaf(hv1.y, w2[4*c+1], d[r]);
        d[r] = fmaf(hv1.z, w2[4*c+2], d[r]);
        d[r] = fmaf(hv1.w, w2[4*c+3], d[r]);
      }
    }
    #pragma unroll
    for (int r = 0; r < ROWS; ++r) {
      gp0[r][tid] = a[r];
      gp1[r][tid] = d[r];
    }
    __syncthreads();

    if (alay == 0) {
      float i_ = gp0[ar][aj]       + gp0[ar][aj + 256];
      float f_ = gp0[ar][aj + 64]  + gp0[ar][aj + 320];
      float gg = gp0[ar][aj + 128] + gp0[ar][aj + 384];
      float o_ = gp0[ar][aj + 192] + gp0[ar][aj + 448];
      c_reg = sigf(f_) * c_reg + sigf(i_) * tanh_fast(gg);
      h0s[ar][aj] = sigf(o_) * tanh_fast(c_reg);
    } else if (t > 0) {
      float i_ = gp1[ar][aj]       + gp1[ar][aj + 256];
      float f_ = gp1[ar][aj + 64]  + gp1[ar][aj + 320];
      float gg = gp1[ar][aj + 128] + gp1[ar][aj + 384];
      float o_ = gp1[ar][aj + 192] + gp1[ar][aj + 448];
      c_reg = sigf(f_) * c_reg + sigf(i_) * tanh_fast(gg);
      h1s[ar][aj] = sigf(o_) * tanh_fast(c_reg);
    }
    __syncthreads();
    #pragma unroll
    for (int r = 0; r < ROWS; ++r) { xwA[r] = xwB[r]; xwB[r] = xwC[r]; xwC[r] = xwD[r]; }
  }

  // final layer-1 step (t = SEQ-1): h0s holds h0_{1023}, h1s holds h1_{1022}
  {
    float d[ROWS];
    #pragma unroll
    for (int r = 0; r < ROWS; ++r) d[r] = bias1;
    #pragma unroll
    for (int c = 0; c < 8; ++c) {
      #pragma unroll
      for (int r = 0; r < ROWS; ++r) {
        float4 hv0 = *(const float4*)&h0s[r][hb * 32 + c * 4];
        float4 hv1 = *(const float4*)&h1s[r][hb * 32 + c * 4];
        d[r] = fmaf(hv0.x, w1[4*c],   d[r]);
        d[r] = fmaf(hv0.y, w1[4*c+1], d[r]);
        d[r] = fmaf(hv0.z, w1[4*c+2], d[r]);
        d[r] = fmaf(hv0.w, w1[4*c+3], d[r]);
        d[r] = fmaf(hv1.x, w2[4*c],   d[r]);
        d[r] = fmaf(hv1.y, w2[4*c+1], d[r]);
        d[r] = fmaf(hv1.z, w2[4*c+2], d[r]);
        d[r] = fmaf(hv1.w, w2[4*c+3], d[r]);
      }
    }
    #pragma unroll
    for (int r = 0; r < ROWS; ++r) gp1[r][tid] = d[r];
    __syncthreads();
    if (alay == 1) {
      float i_ = gp1[ar][aj]       + gp1[ar][aj + 256];
      float f_ = gp1[ar][aj + 64]  + gp1[ar][aj + 320];
      float gg = gp1[ar][aj + 128] + gp1[ar][aj + 384];
      float o_ = gp1[ar][aj + 192] + gp1[ar][aj + 448];
      c_reg = sigf(f_) * c_reg + sigf(i_) * tanh_fast(gg);
      h1s[ar][aj] = sigf(o_) * tanh_fast(c_reg);
    }
    __syncthreads();
  }

  // classifier: z = relu(h1 @ W1.T + b1); out = sigmoid(z . W2 + b2)
  if (alay == 0) {
    const float4* w1p = (const float4*)(W1 + aj * HID);
    float z0 = clsb1[aj], z1 = 0.f, z2 = 0.f, z3 = 0.f;
    #pragma unroll
    for (int c = 0; c < 16; ++c) {
      float4 wv = w1p[c];
      float4 hv = *(const float4*)&h1s[ar][c * 4];
      z0 = fmaf(hv.x, wv.x, z0);
      z1 = fmaf(hv.y, wv.y, z1);
      z2 = fmaf(hv.z, wv.z, z2);
      z3 = fmaf(hv.w, wv.w, z3);
    }
    float z = (z0 + z1) + (z2 + z3);
    z = fmaxf(z, 0.f);
    zs[ar][aj] = z * W2[aj];
  }
  __syncthreads();
  if (tid < ROWS) {
    float s = clsb2[0];
    #pragma unroll
    for (int k = 0; k < HID; ++k) s += zs[tid][k];
    out[brow0 + tid] = sigf(s);
  }
}

extern "C" void kernel_launch(void* const* d_in, const int* in_sizes, int n_in,
                              void* d_out, int out_size, void* d_ws, size_t ws_size,
                              hipStream_t stream) {
  const int*   x    = (const int*)d_in[0];
  const float* emb  = (const float*)d_in[1];
  const float* Wih0 = (const float*)d_in[2];
  const float* Whh0 = (const float*)d_in[3];
  const float* bih0 = (const float*)d_in[4];
  const float* bhh0 = (const float*)d_in[5];
  const float* Wih1 = (const float*)d_in[6];
  const float* Whh1 = (const float*)d_in[7];
  const float* bih1 = (const float*)d_in[8];
  const float* bhh1 = (const float*)d_in[9];
  const float* W1   = (const float*)d_in[10];
  const float* b1   = (const float*)d_in[11];
  const float* W2   = (const float*)d_in[12];
  const float* b2   = (const float*)d_in[13];
  float* out = (float*)d_out;

  char* ws = (char*)d_ws;
  const size_t XW0_BYTES = (size_t)BATCH * SEQ * G4 * sizeof(float);  // 134217728
  float* xw0   = (float*)ws;
  float* Wih0T = (float*)(ws + XW0_BYTES);
  float* b0c   = (float*)(ws + XW0_BYTES + EMB_D * G4 * sizeof(float));
  float* b1c   = (float*)(ws + XW0_BYTES + EMB_D * G4 * sizeof(float) + G4 * sizeof(float));

  prep_kernel<<<1, 256, 0, stream>>>(Wih0, bih0, bhh0, bih1, bhh1, Wih0T, b0c, b1c);
  xw0_kernel<<<(BATCH * SEQ) / TOK, 256, 0, stream>>>(x, emb, Wih0T, b0c, xw0);
  lstm_fused_kernel<<<BATCH / ROWS, 512, 0, stream>>>(xw0, Whh0, Wih1, Whh1, b1c,
                                                      W1, b1, W2, b2, out);
}

// Round 6
// 1025.993 us; speedup vs baseline: 2.6031x; 2.6031x over previous
//
#include <hip/hip_runtime.h>
#include <hip/hip_bf16.h>

#define EMB_D 100
#define HID 64
#define G4 256
#define BATCH 128
#define SEQ 1024
#define TOK 16

typedef _Float16 half2v __attribute__((ext_vector_type(2)));

__device__ __forceinline__ float sigf(float x) { return 1.0f / (1.0f + __expf(-x)); }
__device__ __forceinline__ float tanh_fast(float x) {
  float t = __expf(-2.0f * fabsf(x));
  float r = (1.0f - t) / (1.0f + t);
  return copysignf(r, x);
}

__device__ __forceinline__ float dot2(unsigned int h, unsigned int w, float acc) {
#if __has_builtin(__builtin_amdgcn_fdot2)
  return __builtin_amdgcn_fdot2(__builtin_bit_cast(half2v, h),
                                __builtin_bit_cast(half2v, w), acc, false);
#else
  float r;
  asm("v_dot2_f32_f16 %0, %1, %2, %3" : "=v"(r) : "v"(h), "v"(w), "v"(acc));
  return r;
#endif
}

__device__ __forceinline__ unsigned int packh2(float lo, float hi) {
  unsigned short a = __builtin_bit_cast(unsigned short, (_Float16)lo);
  unsigned short b = __builtin_bit_cast(unsigned short, (_Float16)hi);
  return (unsigned int)a | ((unsigned int)b << 16);
}

// --- prep: combined biases, transposed Wih0, f16-packed recurrent weights ---
__global__ void prep_kernel(const float* __restrict__ Wih0,
                            const float* __restrict__ Whh0, const float* __restrict__ Wih1,
                            const float* __restrict__ Whh1,
                            const float* __restrict__ bih0, const float* __restrict__ bhh0,
                            const float* __restrict__ bih1, const float* __restrict__ bhh1,
                            float* __restrict__ Wih0T, float* __restrict__ b0c,
                            float* __restrict__ b1c,
                            unsigned int* __restrict__ Whh0h,
                            unsigned int* __restrict__ Wih1h,
                            unsigned int* __restrict__ Whh1h) {
  int g = threadIdx.x;   // 0..255 = gate row
  b0c[g] = bih0[g] + bhh0[g];
  b1c[g] = bih1[g] + bhh1[g];
  for (int d = 0; d < EMB_D; ++d) Wih0T[d * G4 + g] = Wih0[g * EMB_D + d];
  for (int d = 0; d < HID / 2; ++d) {
    Whh0h[g * 32 + d] = packh2(Whh0[g * HID + 2 * d], Whh0[g * HID + 2 * d + 1]);
    Wih1h[g * 32 + d] = packh2(Wih1[g * HID + 2 * d], Wih1[g * HID + 2 * d + 1]);
    Whh1h[g * 32 + d] = packh2(Whh1[g * HID + 2 * d], Whh1[g * HID + 2 * d + 1]);
  }
}

// --- xw0[token][gate] = emb[x[token]] . Wih0[gate] + b0, stored f16 ---
__global__ __attribute__((amdgpu_waves_per_eu(1, 4))) __launch_bounds__(256)
void xw0_kernel(
    const int* __restrict__ x, const float* __restrict__ emb,
    const float* __restrict__ Wih0T, const float* __restrict__ b0c,
    _Float16* __restrict__ xw0h) {
  __shared__ int sidx[TOK];
  __shared__ float erow[TOK][EMB_D];
  int g = threadIdx.x;
  long t0 = (long)blockIdx.x * TOK;

  if (g < TOK) sidx[g] = x[t0 + g];
  __syncthreads();
  for (int i = g; i < TOK * EMB_D; i += 256) {
    int tok = i / EMB_D;
    int d = i - tok * EMB_D;
    erow[tok][d] = emb[(long)sidx[tok] * EMB_D + d];
  }

  float w[EMB_D];
  #pragma unroll
  for (int d = 0; d < EMB_D; ++d) w[d] = Wih0T[d * G4 + g];
  float bb = b0c[g];
  __syncthreads();

  for (int tok = 0; tok < TOK; ++tok) {
    const float* ev = erow[tok];
    float a0 = bb, a1 = 0.f, a2 = 0.f, a3 = 0.f;
    #pragma unroll
    for (int d = 0; d < EMB_D; d += 4) {
      a0 = fmaf(w[d],     ev[d],     a0);
      a1 = fmaf(w[d + 1], ev[d + 1], a1);
      a2 = fmaf(w[d + 2], ev[d + 2], a2);
      a3 = fmaf(w[d + 3], ev[d + 3], a3);
    }
    xw0h[(t0 + tok) * G4 + g] = (_Float16)((a0 + a1) + (a2 + a3));
  }
}

// --- fused 2-layer recurrence, in-wave gate quartets, 1 barrier/step ---
// 128 blocks (1 row), 512 threads = 8 waves. Waves 0-3: layer0, waves 4-7:
// layer1. Lane 4m+k of wave w computes the FULL dot for gate k of element
// e = 16*eg + m  (eg = w&3). Quartet (i,f,g,o) -> 3 shfl_xor, activation in
// all lanes, lane k==0 writes h (f16) to double-buffered LDS.
__global__ __launch_bounds__(512, 2) void lstm_fused_kernel(
    const _Float16* __restrict__ xw0h,
    const unsigned int* __restrict__ Whh0h, const unsigned int* __restrict__ Wih1h,
    const unsigned int* __restrict__ Whh1h, const float* __restrict__ b1c,
    const float* __restrict__ W1, const float* __restrict__ clsb1,
    const float* __restrict__ W2, const float* __restrict__ clsb2,
    float* __restrict__ out) {
  int tid = threadIdx.x;
  int lane = tid & 63;
  int w = tid >> 6;
  bool isL1 = (w >= 4);
  int eg = isL1 ? (w - 4) : w;
  int e = eg * 16 + (lane >> 2);
  int k = lane & 3;
  int row = k * HID + e;          // gate row in [0,256)
  int b = blockIdx.x;

  __shared__ alignas(16) _Float16 h0s[2][HID];
  __shared__ alignas(16) _Float16 h1s[2][HID];
  __shared__ alignas(16) float hf[HID];

  // per-lane weight rows, f16-packed: L0 = Whh0 row; L1 = Wih1 + Whh1 rows
  uint4 wA[8], wB[8];
  if (!isL1) {
    const uint4* p = (const uint4*)(Whh0h + row * 32);
    #pragma unroll
    for (int c = 0; c < 8; ++c) wA[c] = p[c];
  } else {
    const uint4* p = (const uint4*)(Wih1h + row * 32);
    const uint4* q = (const uint4*)(Whh1h + row * 32);
    #pragma unroll
    for (int c = 0; c < 8; ++c) { wA[c] = p[c]; wB[c] = q[c]; }
  }
  float bias = isL1 ? b1c[row] : 0.f;

  if (tid < 2 * HID) {
    int j = tid & (HID - 1);
    if (tid < HID) { h0s[0][j] = (_Float16)0.f; h0s[1][j] = (_Float16)0.f; }
    else           { h1s[0][j] = (_Float16)0.f; h1s[1][j] = (_Float16)0.f; }
  }

  const _Float16* xr = xw0h + (long)b * SEQ * G4 + row;
  float xw_t = 0.f, xw_t1 = 0.f;
  if (!isL1) { xw_t = (float)xr[0]; xw_t1 = (float)xr[G4]; }
  float c_reg = 0.f;
  __syncthreads();

  for (int t = 0; t < SEQ; ++t) {
    float xw_t2 = 0.f;
    if (!isL1) {
      int tn = (t + 2 < SEQ) ? (t + 2) : (SEQ - 1);
      xw_t2 = (float)xr[(long)tn * G4];
    }
    int rb = (t + 1) & 1, wbuf = t & 1;
    const uint4* h0p = (const uint4*)h0s[rb];
    float a0, a1 = 0.f, a2 = 0.f, a3 = 0.f;
    if (!isL1) {
      a0 = xw_t;
      #pragma unroll
      for (int c = 0; c < 8; ++c) {
        uint4 h = h0p[c];
        a0 = dot2(h.x, wA[c].x, a0);
        a1 = dot2(h.y, wA[c].y, a1);
        a2 = dot2(h.z, wA[c].z, a2);
        a3 = dot2(h.w, wA[c].w, a3);
      }
    } else {
      const uint4* h1p = (const uint4*)h1s[rb];
      a0 = bias;
      #pragma unroll
      for (int c = 0; c < 8; ++c) {
        uint4 h = h0p[c];
        a0 = dot2(h.x, wA[c].x, a0);
        a1 = dot2(h.y, wA[c].y, a1);
        a2 = dot2(h.z, wA[c].z, a2);
        a3 = dot2(h.w, wA[c].w, a3);
      }
      #pragma unroll
      for (int c = 0; c < 8; ++c) {
        uint4 h = h1p[c];
        a0 = dot2(h.x, wB[c].x, a0);
        a1 = dot2(h.y, wB[c].y, a1);
        a2 = dot2(h.z, wB[c].z, a2);
        a3 = dot2(h.w, wB[c].w, a3);
      }
    }
    float gown = (a0 + a1) + (a2 + a3);
    float gx1 = __shfl_xor(gown, 1);
    float gx2 = __shfl_xor(gown, 2);
    float gx3 = __shfl_xor(gx1, 2);
    // valid in lanes with k==0: i=gown, f=gx1, g=gx2, o=gx3
    bool act = (!isL1) || (t > 0);
    if (act) {
      c_reg = sigf(gx1) * c_reg + sigf(gown) * tanh_fast(gx2);
      float hv = sigf(gx3) * tanh_fast(c_reg);
      if (k == 0) {
        _Float16 h16 = (_Float16)hv;
        if (isL1) h1s[wbuf][e] = h16; else h0s[wbuf][e] = h16;
      }
    }
    xw_t = xw_t1; xw_t1 = xw_t2;
    __syncthreads();
  }

  // extra layer-1 step: h1[1023] from h0[1023], h1[1022] (both in buf 1)
  if (isL1) {
    const uint4* h0p = (const uint4*)h0s[1];
    const uint4* h1p = (const uint4*)h1s[1];
    float a0 = bias, a1 = 0.f, a2 = 0.f, a3 = 0.f;
    #pragma unroll
    for (int c = 0; c < 8; ++c) {
      uint4 h = h0p[c];
      a0 = dot2(h.x, wA[c].x, a0);
      a1 = dot2(h.y, wA[c].y, a1);
      a2 = dot2(h.z, wA[c].z, a2);
      a3 = dot2(h.w, wA[c].w, a3);
    }
    #pragma unroll
    for (int c = 0; c < 8; ++c) {
      uint4 h = h1p[c];
      a0 = dot2(h.x, wB[c].x, a0);
      a1 = dot2(h.y, wB[c].y, a1);
      a2 = dot2(h.z, wB[c].z, a2);
      a3 = dot2(h.w, wB[c].w, a3);
    }
    float gown = (a0 + a1) + (a2 + a3);
    float gx1 = __shfl_xor(gown, 1);
    float gx2 = __shfl_xor(gown, 2);
    float gx3 = __shfl_xor(gx1, 2);
    c_reg = sigf(gx1) * c_reg + sigf(gown) * tanh_fast(gx2);
    float hv = sigf(gx3) * tanh_fast(c_reg);
    if (k == 0) hf[e] = hv;
  }
  __syncthreads();

  // classifier (wave 0): z = relu(h1.W1^T + b1); out = sigmoid(z.W2 + b2)
  if (w == 0) {
    int j = lane;
    const float4* wp = (const float4*)(W1 + j * HID);
    const float4* hp = (const float4*)hf;
    float z0 = clsb1[j], z1 = 0.f, z2 = 0.f, z3 = 0.f;
    #pragma unroll
    for (int c = 0; c < 16; ++c) {
      float4 wv = wp[c];
      float4 hv = hp[c];
      z0 = fmaf(hv.x, wv.x, z0);
      z1 = fmaf(hv.y, wv.y, z1);
      z2 = fmaf(hv.z, wv.z, z2);
      z3 = fmaf(hv.w, wv.w, z3);
    }
    float z = fmaxf((z0 + z1) + (z2 + z3), 0.f);
    float v = z * W2[j];
    v += __shfl_xor(v, 1);
    v += __shfl_xor(v, 2);
    v += __shfl_xor(v, 4);
    v += __shfl_xor(v, 8);
    v += __shfl_xor(v, 16);
    v += __shfl_xor(v, 32);
    if (lane == 0) out[b] = sigf(v + clsb2[0]);
  }
}

extern "C" void kernel_launch(void* const* d_in, const int* in_sizes, int n_in,
                              void* d_out, int out_size, void* d_ws, size_t ws_size,
                              hipStream_t stream) {
  const int*   x    = (const int*)d_in[0];
  const float* emb  = (const float*)d_in[1];
  const float* Wih0 = (const float*)d_in[2];
  const float* Whh0 = (const float*)d_in[3];
  const float* bih0 = (const float*)d_in[4];
  const float* bhh0 = (const float*)d_in[5];
  const float* Wih1 = (const float*)d_in[6];
  const float* Whh1 = (const float*)d_in[7];
  const float* bih1 = (const float*)d_in[8];
  const float* bhh1 = (const float*)d_in[9];
  const float* W1   = (const float*)d_in[10];
  const float* b1   = (const float*)d_in[11];
  const float* W2   = (const float*)d_in[12];
  const float* b2   = (const float*)d_in[13];
  float* out = (float*)d_out;

  char* ws = (char*)d_ws;
  const size_t XW0_BYTES = (size_t)BATCH * SEQ * G4 * sizeof(_Float16);  // 67108864
  _Float16* xw0h = (_Float16*)ws;                 ws += XW0_BYTES;
  float* Wih0T   = (float*)ws;                    ws += (size_t)EMB_D * G4 * sizeof(float);
  float* b0c     = (float*)ws;                    ws += G4 * sizeof(float);
  float* b1c     = (float*)ws;                    ws += G4 * sizeof(float);
  unsigned int* Whh0h = (unsigned int*)ws;        ws += (size_t)G4 * 32 * sizeof(unsigned int);
  unsigned int* Wih1h = (unsigned int*)ws;        ws += (size_t)G4 * 32 * sizeof(unsigned int);
  unsigned int* Whh1h = (unsigned int*)ws;        ws += (size_t)G4 * 32 * sizeof(unsigned int);

  prep_kernel<<<1, 256, 0, stream>>>(Wih0, Whh0, Wih1, Whh1, bih0, bhh0, bih1, bhh1,
                                     Wih0T, b0c, b1c, Whh0h, Wih1h, Whh1h);
  xw0_kernel<<<(BATCH * SEQ) / TOK, 256, 0, stream>>>(x, emb, Wih0T, b0c, xw0h);
  lstm_fused_kernel<<<BATCH, 512, 0, stream>>>(xw0h, Whh0h, Wih1h, Whh1h, b1c,
                                               W1, b1, W2, b2, out);
}